// Round 1
// baseline (657.299 us; speedup 1.0000x reference)
//
#include <hip/hip_runtime.h>
#include <math.h>

#define BB 8
#define HH 384
#define WW 384
#define CC 3
#define NPAR 6
#define DEL 10
#define MAXIT 12
#define NTILES 128
#define HWPIX (HH*WW)           // 147456
#define TILE_ (HWPIX/NTILES)    // 1152
#define NACC 24

__device__ __forceinline__ float cubicw(float s) {
    s = fabsf(s);
    float s2 = s * s, s3 = s2 * s;
    float w1 = 1.5f * s3 - 2.5f * s2 + 1.0f;
    float w2 = -0.5f * s3 + 2.5f * s2 - 4.0f * s + 2.0f;
    return (s <= 1.0f) ? w1 : ((s < 2.0f) ? w2 : 0.0f);
}

// bicubic sample of 3 channels at (xg,yg), clip-to-edge, Keys a=-0.5
__device__ __forceinline__ void bicubic3(const float* __restrict__ Ib, double xg, double yg, float Iw[3]) {
    double fx = floor(xg), fy = floor(yg);
    float tx = (float)(xg - fx), ty = (float)(yg - fy);
    int xi = (int)fmax(fmin(fx, 1.0e9), -1.0e9);
    int yi = (int)fmax(fmin(fy, 1.0e9), -1.0e9);
    float wx[4], wyv[4];
    int xx[4], yy[4];
#pragma unroll
    for (int k = 0; k < 4; k++) {
        wx[k]  = cubicw(tx - (float)(k - 1));
        wyv[k] = cubicw(ty - (float)(k - 1));
        xx[k] = min(max(xi + k - 1, 0), WW - 1);
        yy[k] = min(max(yi + k - 1, 0), HH - 1);
    }
    Iw[0] = 0.f; Iw[1] = 0.f; Iw[2] = 0.f;
#pragma unroll
    for (int j = 0; j < 4; j++) {
        const float* row = Ib + yy[j] * (WW * CC);
        float r0 = 0.f, r1 = 0.f, r2 = 0.f;
#pragma unroll
        for (int k = 0; k < 4; k++) {
            const float* q = row + xx[k] * CC;
            r0 = fmaf(wx[k], q[0], r0);
            r1 = fmaf(wx[k], q[1], r1);
            r2 = fmaf(wx[k], q[2], r2);
        }
        Iw[0] = fmaf(wyv[j], r0, Iw[0]);
        Iw[1] = fmaf(wyv[j], r1, Iw[1]);
        Iw[2] = fmaf(wyv[j], r2, Iw[2]);
    }
}

extern "C" __global__ void k_init(const float* __restrict__ p0, double* __restrict__ p_store,
                                  int* __restrict__ done0) {
    int tid = threadIdx.x;
    if (tid < BB * NPAR) p_store[tid] = (double)p0[tid];
    if (tid < BB) done0[tid] = 0;
}

extern "C" __global__ __launch_bounds__(256)
void k_warp_reduce(const float* __restrict__ I1, const float* __restrict__ I2,
                   const double* __restrict__ p_cur, const int* __restrict__ done_cur,
                   double* __restrict__ partials) {
    const int b = blockIdx.y;
    const int tile = blockIdx.x;
    const int tid = threadIdx.x;
    if (done_cur[b]) return;  // frozen batch: solve ignores stale partials

    const double* p = p_cur + b * NPAR;
    const double M00 = 1.0 + p[2], M01 = p[3], M02 = p[0];
    const double M10 = p[4], M11 = 1.0 + p[5], M12 = p[1];
    const float* I1b = I1 + (size_t)b * HWPIX * CC;
    const float* I2b = I2 + (size_t)b * HWPIX * CC;

    double acc[NACC];
#pragma unroll
    for (int i = 0; i < NACC; i++) acc[i] = 0.0;

    const int pend = (tile + 1) * TILE_;
    for (int pix = tile * TILE_ + tid; pix < pend; pix += 256) {
        const int y = pix / WW;
        const int x = pix - y * WW;
        if (x < DEL || x >= WW - DEL || y < DEL || y >= HH - DEL) continue;  // valid1
        const double xg = M00 * (double)x + M01 * (double)y + M02;
        const double yg = M10 * (double)x + M11 * (double)y + M12;
        const double gx = rint(xg), gy = rint(yg);  // half-to-even like jnp.round
        if (!(gx >= (double)DEL && gx <= (double)(WW - DEL) &&
              gy >= (double)DEL && gy <= (double)(HH - DEL))) continue;      // wmask

        float Iw[3];
        bicubic3(I2b, xg, yg, Iw);

        const float* c  = I1b + pix * CC;
        const float* cl = c - CC;
        const float* cr = c + CC;
        const float* cu = c - WW * CC;
        const float* cd = c + WW * CC;

        float Af = 0.f, Bf = 0.f, Cf = 0.f, T0f = 0.f, T1f = 0.f;
#pragma unroll
        for (int ch = 0; ch < 3; ch++) {
            const float Ix = (cr[ch] - cl[ch]) * 0.5f;   // interior: matches padded central diff
            const float Iy = (cd[ch] - cu[ch]) * 0.5f;
            const float d = Iw[ch] - c[ch];
            const float u = d * 20.0f;                    // DI/LAM
            const float w = 1.0f / sqrtf(fmaf(u, u, 1.0f));
            const float wd = w * d;
            T0f = fmaf(Ix, wd, T0f);
            T1f = fmaf(Iy, wd, T1f);
            const float wIx = w * Ix;
            Af = fmaf(wIx, Ix, Af);
            Bf = fmaf(wIx, Iy, Bf);
            Cf = fmaf(w * Iy, Iy, Cf);
        }
        const double X = (double)x, Y = (double)y;
        const double XX_ = X * X, XY_ = X * Y, YY_ = Y * Y;
        const double T0 = (double)T0f, T1 = (double)T1f;
        const double A = (double)Af, Bd = (double)Bf, Cd = (double)Cf;
        acc[0] += T0;  acc[1] += T0 * X;  acc[2] += T0 * Y;
        acc[3] += T1;  acc[4] += T1 * X;  acc[5] += T1 * Y;
        acc[6] += A;   acc[7] += A * X;   acc[8] += A * Y;
        acc[9] += A * XX_;  acc[10] += A * XY_;  acc[11] += A * YY_;
        acc[12] += Bd; acc[13] += Bd * X; acc[14] += Bd * Y;
        acc[15] += Bd * XX_; acc[16] += Bd * XY_; acc[17] += Bd * YY_;
        acc[18] += Cd; acc[19] += Cd * X; acc[20] += Cd * Y;
        acc[21] += Cd * XX_; acc[22] += Cd * XY_; acc[23] += Cd * YY_;
    }

    // wave shuffle reduce (64 lanes), then cross-wave via LDS — deterministic
#pragma unroll
    for (int a = 0; a < NACC; a++) {
        double v = acc[a];
#pragma unroll
        for (int off = 32; off >= 1; off >>= 1) v += __shfl_down(v, off, 64);
        acc[a] = v;
    }
    __shared__ double wsum[4][NACC];
    const int lane = tid & 63, wid = tid >> 6;
    if (lane == 0) {
#pragma unroll
        for (int a = 0; a < NACC; a++) wsum[wid][a] = acc[a];
    }
    __syncthreads();
    if (tid < NACC) {
        double s = wsum[0][tid] + wsum[1][tid] + wsum[2][tid] + wsum[3][tid];
        partials[((size_t)b * NTILES + tile) * NACC + tid] = s;
    }
}

extern "C" __global__ __launch_bounds__(256)
void k_solve(const double* __restrict__ partials, const double* __restrict__ p_in,
             const int* __restrict__ done_in, double* __restrict__ p_out,
             int* __restrict__ done_out) {
    __shared__ double S[BB][NACC];
    const int tid = threadIdx.x;
    if (tid < BB * NACC) {
        const int b = tid / NACC, a = tid - b * NACC;
        double s = 0.0;
        for (int t = 0; t < NTILES; t++) s += partials[((size_t)b * NTILES + t) * NACC + a];
        S[b][a] = s;
    }
    __syncthreads();
    if (tid >= BB) return;
    const int b = tid;
    if (done_in[b]) {
        done_out[b] = 1;
        for (int i = 0; i < NPAR; i++) p_out[b * NPAR + i] = p_in[b * NPAR + i];
        return;
    }
    const double* Sb = S[b];
    // bvec: DIJ ordering [Ix, Iy, IxX, IxY, IyX, IyY]
    double bv[6] = {Sb[0], Sb[3], Sb[1], Sb[2], Sb[4], Sb[5]};
    double Hm[6][6];
    Hm[0][0] = Sb[6];  Hm[0][1] = Sb[12]; Hm[0][2] = Sb[7];  Hm[0][3] = Sb[8];  Hm[0][4] = Sb[13]; Hm[0][5] = Sb[14];
    Hm[1][1] = Sb[18]; Hm[1][2] = Sb[13]; Hm[1][3] = Sb[14]; Hm[1][4] = Sb[19]; Hm[1][5] = Sb[20];
    Hm[2][2] = Sb[9];  Hm[2][3] = Sb[10]; Hm[2][4] = Sb[15]; Hm[2][5] = Sb[16];
    Hm[3][3] = Sb[11]; Hm[3][4] = Sb[16]; Hm[3][5] = Sb[17];
    Hm[4][4] = Sb[21]; Hm[4][5] = Sb[22];
    Hm[5][5] = Sb[23];
    for (int i = 0; i < 6; i++)
        for (int j = 0; j < i; j++) Hm[i][j] = Hm[j][i];
    for (int i = 0; i < 6; i++) Hm[i][i] += 1e-6;

    // 6x6 Gaussian elimination with partial pivoting (fp64)
    double Aa[6][7];
    for (int i = 0; i < 6; i++) {
        for (int j = 0; j < 6; j++) Aa[i][j] = Hm[i][j];
        Aa[i][6] = bv[i];
    }
    for (int k = 0; k < 6; k++) {
        int piv = k;
        double mx = fabs(Aa[k][k]);
        for (int r = k + 1; r < 6; r++) {
            double v = fabs(Aa[r][k]);
            if (v > mx) { mx = v; piv = r; }
        }
        if (piv != k)
            for (int j = k; j < 7; j++) { double t = Aa[k][j]; Aa[k][j] = Aa[piv][j]; Aa[piv][j] = t; }
        const double inv = 1.0 / Aa[k][k];
        for (int r = k + 1; r < 6; r++) {
            const double f = Aa[r][k] * inv;
            for (int j = k; j < 7; j++) Aa[r][j] -= f * Aa[k][j];
        }
    }
    double dp[6];
    for (int i = 5; i >= 0; i--) {
        double s = Aa[i][6];
        for (int j = i + 1; j < 6; j++) s -= Aa[i][j] * dp[j];
        dp[i] = s / Aa[i][i];
    }
    const double nrm = sqrt(dp[0]*dp[0] + dp[1]*dp[1] + dp[2]*dp[2] + dp[3]*dp[3] + dp[4]*dp[4] + dp[5]*dp[5]);
    const int conv = (nrm < 1e-3) ? 1 : 0;

    // Mn = M(p) @ inv(M(dp));  affine 3x3, bottom row [0,0,1]
    const double* pc = p_in + b * NPAR;
    const double m00 = 1.0 + pc[2], m01 = pc[3], m02 = pc[0];
    const double m10 = pc[4], m11 = 1.0 + pc[5], m12 = pc[1];
    const double q00 = 1.0 + dp[2], q01 = dp[3], q02 = dp[0];
    const double q10 = dp[4], q11 = 1.0 + dp[5], q12 = dp[1];
    const double det = q00 * q11 - q01 * q10;
    const double i00 = q11 / det, i01 = -q01 / det;
    const double i10 = -q10 / det, i11 = q00 / det;
    const double it0 = -(i00 * q02 + i01 * q12);
    const double it1 = -(i10 * q02 + i11 * q12);
    const double n00 = m00 * i00 + m01 * i10;
    const double n01 = m00 * i01 + m01 * i11;
    const double n02 = m00 * it0 + m01 * it1 + m02;
    const double n10 = m10 * i00 + m11 * i10;
    const double n11 = m10 * i01 + m11 * i11;
    const double n12 = m10 * it0 + m11 * it1 + m12;
    // Mn[2][2] == 1 exactly for affine composition
    p_out[b * NPAR + 0] = n02;
    p_out[b * NPAR + 1] = n12;
    p_out[b * NPAR + 2] = n00 - 1.0;
    p_out[b * NPAR + 3] = n01;
    p_out[b * NPAR + 4] = n10;
    p_out[b * NPAR + 5] = n11 - 1.0;
    done_out[b] = conv;
}

extern "C" __global__ __launch_bounds__(256)
void k_final_map(const float* __restrict__ I1, const float* __restrict__ I2,
                 const double* __restrict__ p_fin, float* __restrict__ DI_out,
                 float* __restrict__ Iw_out, double* __restrict__ fpart) {
    const int b = blockIdx.y;
    const int tile = blockIdx.x;
    const int tid = threadIdx.x;
    const double* p = p_fin + b * NPAR;
    const double M00 = 1.0 + p[2], M01 = p[3], M02 = p[0];
    const double M10 = p[4], M11 = 1.0 + p[5], M12 = p[1];
    const float* I1b = I1 + (size_t)b * HWPIX * CC;
    const float* I2b = I2 + (size_t)b * HWPIX * CC;
    float* DIb = DI_out + (size_t)b * HWPIX * CC;
    float* Iwb = Iw_out + (size_t)b * HWPIX * CC;

    double rho_s = 0.0, cnt_s = 0.0;
    const int pend = (tile + 1) * TILE_;
    for (int pix = tile * TILE_ + tid; pix < pend; pix += 256) {
        const int y = pix / WW;
        const int x = pix - y * WW;
        const double xg = M00 * (double)x + M01 * (double)y + M02;
        const double yg = M10 * (double)x + M11 * (double)y + M12;
        float Iw[3];
        bicubic3(I2b, xg, yg, Iw);   // Iw written unmasked, all pixels
        Iwb[pix * CC + 0] = Iw[0];
        Iwb[pix * CC + 1] = Iw[1];
        Iwb[pix * CC + 2] = Iw[2];

        const bool v1 = (x >= DEL) && (x < WW - DEL) && (y >= DEL) && (y < HH - DEL);
        const double gx = rint(xg), gy = rint(yg);
        const bool wm = (gx >= (double)DEL && gx <= (double)(WW - DEL) &&
                         gy >= (double)DEL && gy <= (double)(HH - DEL));
        const bool m = v1 && wm;
        const float* c = I1b + pix * CC;
#pragma unroll
        for (int ch = 0; ch < 3; ch++) {
            const float d = m ? (Iw[ch] - c[ch]) : 0.0f;
            DIb[pix * CC + ch] = d;
            if (m) {
                const float u = d * 20.0f;
                const float rho = 0.005f * (sqrtf(fmaf(u, u, 1.0f)) - 1.0f);
                rho_s += (double)rho;
            }
        }
        if (m) cnt_s += 3.0;
    }
#pragma unroll
    for (int off = 32; off >= 1; off >>= 1) {
        rho_s += __shfl_down(rho_s, off, 64);
        cnt_s += __shfl_down(cnt_s, off, 64);
    }
    __shared__ double wsum[4][2];
    const int lane = tid & 63, wid = tid >> 6;
    if (lane == 0) { wsum[wid][0] = rho_s; wsum[wid][1] = cnt_s; }
    __syncthreads();
    if (tid < 2) {
        double s = wsum[0][tid] + wsum[1][tid] + wsum[2][tid] + wsum[3][tid];
        fpart[((size_t)b * NTILES + tile) * 2 + tid] = s;
    }
}

extern "C" __global__ void k_finish(const double* __restrict__ p_fin,
                                    const double* __restrict__ fpart,
                                    float* __restrict__ out) {
    const int tid = threadIdx.x;  // 64 threads
    if (tid < BB * NPAR) out[tid] = (float)p_fin[tid];           // pf
    if (tid >= 48 && tid < 48 + BB) {
        const int b = tid - 48;
        double rs = 0.0, cs = 0.0;
        for (int t = 0; t < NTILES; t++) {
            rs += fpart[((size_t)b * NTILES + t) * 2 + 0];
            cs += fpart[((size_t)b * NTILES + t) * 2 + 1];
        }
        out[48 + b] = (float)(rs / fmax(cs, 1.0));               // err
    }
}

extern "C" void kernel_launch(void* const* d_in, const int* in_sizes, int n_in,
                              void* d_out, int out_size, void* d_ws, size_t ws_size,
                              hipStream_t stream) {
    const float* I1 = (const float*)d_in[0];
    const float* I2 = (const float*)d_in[1];
    const float* p0 = (const float*)d_in[2];
    float* out = (float*)d_out;

    // ws layout (all 8B-aligned):
    // [0)                p_store: (MAXIT+1)*8*6 doubles = 624  (4992 B)
    // [4992)             done:    (MAXIT+1)*8 ints      = 104  (416 B)
    // [5408)             partials: 8*128*24 doubles            (196608 B)
    // [202016)           fpart:    8*128*2 doubles             (16384 B)
    double* p_store = (double*)d_ws;
    int* done_flags = (int*)((char*)d_ws + 4992);
    double* partials = (double*)((char*)d_ws + 5408);
    double* fpart = (double*)((char*)d_ws + 202016);

    dim3 grid(NTILES, BB), blk(256);
    k_init<<<1, 64, 0, stream>>>(p0, p_store, done_flags);
    for (int it = 0; it < MAXIT; it++) {
        k_warp_reduce<<<grid, blk, 0, stream>>>(I1, I2, p_store + (size_t)it * BB * NPAR,
                                                done_flags + it * BB, partials);
        k_solve<<<1, 256, 0, stream>>>(partials, p_store + (size_t)it * BB * NPAR,
                                       done_flags + it * BB,
                                       p_store + (size_t)(it + 1) * BB * NPAR,
                                       done_flags + (it + 1) * BB);
    }
    float* DI_out = out + 56;
    float* Iw_out = out + 56 + (size_t)BB * HWPIX * CC;
    k_final_map<<<grid, blk, 0, stream>>>(I1, I2, p_store + (size_t)MAXIT * BB * NPAR,
                                          DI_out, Iw_out, fpart);
    k_finish<<<1, 64, 0, stream>>>(p_store + (size_t)MAXIT * BB * NPAR, fpart, out);
}